// Round 5
// baseline (1184.471 us; speedup 1.0000x reference)
//
#include <hip/hip_runtime.h>
#include <hip/hip_bf16.h>
#include <stdint.h>

#define E_N 16
#define TOPK 4
#define DD 2560
#define FF 1664
#define FSS 3328
#define TT 2048

typedef __attribute__((ext_vector_type(8))) __bf16 bf16x8;
typedef __attribute__((ext_vector_type(4))) float f32x4;

__device__ __forceinline__ unsigned short f2bf(float f) {
  return __builtin_bit_cast(unsigned short, (__bf16)f);
}
__device__ __forceinline__ unsigned int pk2(float a, float b) {
  return (unsigned int)f2bf(a) | ((unsigned int)f2bf(b) << 16);
}

#define GLOAD16(g, l)                                                          \
  __builtin_amdgcn_global_load_lds(                                            \
      (const __attribute__((address_space(1))) void*)(g),                      \
      (__attribute__((address_space(3))) void*)(l), 16, 0, 0)

#define SBAR() __builtin_amdgcn_s_barrier()
#define SCHED0() __builtin_amdgcn_sched_barrier(0)
#define VMW(N) asm volatile("s_waitcnt vmcnt(" #N ")" ::: "memory")
#define LGKM0() asm volatile("s_waitcnt lgkmcnt(0)" ::: "memory")

// swizzled block decompose: XCD-chunked bijective remap (requires nwg%8==0)
__device__ __forceinline__ void swz_block(int& bm, int& bn, int& bz) {
  int gx = gridDim.x, gy = gridDim.y;
  int nwg = gx * gy * gridDim.z;
  int flat = blockIdx.x + gx * (blockIdx.y + gy * blockIdx.z);
  if ((nwg & 7) == 0) flat = (flat & 7) * (nwg >> 3) + (flat >> 3);
  bm = flat % gx;
  int rest = flat / gx;
  bn = rest % gy;
  bz = rest / gy;
}

// ---------------- X -> bf16 ----------------
__global__ __launch_bounds__(256) void cvt_bf16_kernel(const float* __restrict__ in,
                                                       unsigned short* __restrict__ out) {
  size_t i = ((size_t)blockIdx.x * 256 + threadIdx.x) * 4;
  float4 v = *reinterpret_cast<const float4*>(in + i);
  ushort4 o;
  o.x = f2bf(v.x); o.y = f2bf(v.y); o.z = f2bf(v.z); o.w = f2bf(v.w);
  *reinterpret_cast<ushort4*>(out + i) = o;
}

// ---------------- Router ----------------
__global__ __launch_bounds__(256) void router_kernel(const float* __restrict__ x,
                                                     const float* __restrict__ rw,
                                                     int* __restrict__ cnt,
                                                     int* __restrict__ list,
                                                     float* __restrict__ tw) {
  int t = blockIdx.x;
  const float* xr = x + (size_t)t * DD;
  __shared__ float logits[E_N];
  int lane = threadIdx.x & 63, wid = threadIdx.x >> 6;
  for (int ee = 0; ee < 4; ++ee) {
    int e = wid * 4 + ee;
    const float* wr = rw + (size_t)e * DD;
    float p = 0.f;
    for (int d = lane; d < DD; d += 64) p += xr[d] * wr[d];
#pragma unroll
    for (int off = 32; off > 0; off >>= 1) p += __shfl_down(p, off);
    if (lane == 0) logits[e] = p;
  }
  __syncthreads();
  if (threadIdx.x == 0) {
    float mx = -1e30f;
    for (int e = 0; e < E_N; ++e) mx = fmaxf(mx, logits[e]);
    float pe[E_N];
    for (int e = 0; e < E_N; ++e) pe[e] = __expf(logits[e] - mx);
    int idx[TOPK]; float val[TOPK]; float s4 = 0.f;
    unsigned used = 0;
    for (int k = 0; k < TOPK; ++k) {
      int bi = 0; float bv = -1.f;
      for (int e = 0; e < E_N; ++e)
        if (!((used >> e) & 1) && pe[e] > bv) { bv = pe[e]; bi = e; }
      used |= 1u << bi; idx[k] = bi; val[k] = bv; s4 += bv;
    }
    float inv = 1.f / s4;
    for (int k = 0; k < TOPK; ++k) {
      int e2 = idx[k];
      int pos = atomicAdd(&cnt[e2], 1);
      list[e2 * TT + pos] = t * 4 + k;
      tw[t * 4 + k] = val[k] * inv;
    }
  }
}

// ---------------- fused gate+up grouped GEMM, native f32 [K][N] weights ----------------
// BM=128, BN=128, BK=32, 4 waves (2m x 2n), A via global_load_lds (bf16 gather),
// B via regs: float4 loads along N + cvt_pk + ds_write transposed into [N][K] LDS.
__global__ __launch_bounds__(256, 2) void gu_kernel(
    const unsigned short* __restrict__ Xb,   // [T][Ktot] bf16
    const float* __restrict__ Wg,            // [E][Ktot][Ntot] f32 native
    const float* __restrict__ Wu,
    unsigned short* __restrict__ H,          // [codes][Ntot] bf16
    const int* __restrict__ list, const int* __restrict__ cnt,
    int Ktot, int Ntot, int Mfixed) {
  int bm, bn, e;
  swz_block(bm, bn, e);
  int M = cnt ? cnt[e] : Mfixed;
  int m0 = bm * 128;
  if (m0 >= M) return;
  int n0 = bn * 128;
  const float* G0 = Wg + (size_t)e * Ktot * Ntot;
  const float* U0 = Wu + (size_t)e * Ktot * Ntot;
  const int* lst = list ? (list + e * TT) : nullptr;

  __shared__ __align__(16) unsigned short sA[2][4096];
  __shared__ __align__(16) unsigned short sG[2][4096];
  __shared__ __align__(16) unsigned short sU[2][4096];

  int tid = threadIdx.x, lane = tid & 63, w = tid >> 6;

  // A gather: issue q covers rows q*64 + (tid>>2), chunk (tid&3), source pre-swizzled
  const unsigned short* pA[2];
#pragma unroll
  for (int q = 0; q < 2; ++q) {
    int row = q * 64 + (tid >> 2);
    int cs = (tid & 3) ^ ((row >> 1) & 3);
    int ar = min(m0 + row, M - 1);
    int tok = lst ? (lst[ar] >> 2) : ar;
    pA[q] = Xb + (size_t)tok * Ktot + cs * 8;
  }

  // B: thread owns 4x4 f32 block at (k = kq*4 + j, n = nq*4 .. +3)
  int kq = tid >> 5, nq = tid & 31;
  const float* pG = G0 + (size_t)(kq * 4) * Ntot + n0 + nq * 4;
  const float* pU = U0 + (size_t)(kq * 4) * Ntot + n0 + nq * 4;

  // ds_write offsets (ushorts) for the 4 transposed rows
  int wB[4];
#pragma unroll
  for (int i = 0; i < 4; ++i) {
    int r = nq * 4 + i;
    wB[i] = r * 32 + (((kq >> 1) ^ ((r >> 1) & 3)) * 8) + ((kq & 1) * 4);
  }

  // fragment read offsets
  int wm = w >> 1, wn = w & 1, cg = lane >> 4;
  int aoff[4], boff[4];
#pragma unroll
  for (int mf = 0; mf < 4; ++mf) {
    int r = wm * 64 + mf * 16 + (lane & 15);
    aoff[mf] = r * 32 + ((cg ^ ((r >> 1) & 3)) * 8);
  }
#pragma unroll
  for (int nf = 0; nf < 4; ++nf) {
    int rb = wn * 64 + nf * 16 + (lane & 15);
    boff[nf] = rb * 32 + ((cg ^ ((rb >> 1) & 3)) * 8);
  }

  f32x4 accG[4][4] = {};
  f32x4 accU[4][4] = {};
  float4 rG[4], rU[4];

  auto issueA = [&](int kt, int b) {
    GLOAD16(pA[0] + kt * 32, &sA[b][tid * 8]);
    GLOAD16(pA[1] + kt * 32, &sA[b][2048 + tid * 8]);
  };
  auto issueB = [&](int kt) {
#pragma unroll
    for (int j = 0; j < 4; ++j) {
      rG[j] = *reinterpret_cast<const float4*>(pG + (size_t)(kt * 32 + j) * Ntot);
      rU[j] = *reinterpret_cast<const float4*>(pU + (size_t)(kt * 32 + j) * Ntot);
    }
  };
  auto writeB = [&](int b) {
#pragma unroll
    for (int i = 0; i < 4; ++i) {
      uint2 vg{pk2(rG[0][i], rG[1][i]), pk2(rG[2][i], rG[3][i])};
      uint2 vu{pk2(rU[0][i], rU[1][i]), pk2(rU[2][i], rU[3][i])};
      *reinterpret_cast<uint2*>(&sG[b][wB[i]]) = vg;
      *reinterpret_cast<uint2*>(&sU[b][wB[i]]) = vu;
    }
  };
  auto compute = [&](int b) {
    bf16x8 a[4], g[4], u[4];
#pragma unroll
    for (int mf = 0; mf < 4; ++mf)
      a[mf] = __builtin_bit_cast(bf16x8, *reinterpret_cast<const uint4*>(&sA[b][aoff[mf]]));
#pragma unroll
    for (int nf = 0; nf < 4; ++nf) {
      g[nf] = __builtin_bit_cast(bf16x8, *reinterpret_cast<const uint4*>(&sG[b][boff[nf]]));
      u[nf] = __builtin_bit_cast(bf16x8, *reinterpret_cast<const uint4*>(&sU[b][boff[nf]]));
    }
    __builtin_amdgcn_s_setprio(1);
#pragma unroll
    for (int mf = 0; mf < 4; ++mf)
#pragma unroll
      for (int nf = 0; nf < 4; ++nf) {
        accG[mf][nf] = __builtin_amdgcn_mfma_f32_16x16x32_bf16(a[mf], g[nf], accG[mf][nf], 0, 0, 0);
        accU[mf][nf] = __builtin_amdgcn_mfma_f32_16x16x32_bf16(a[mf], u[nf], accU[mf][nf], 0, 0, 0);
      }
    __builtin_amdgcn_s_setprio(0);
  };

  int nk = Ktot / 32;
  issueB(0);
  SCHED0();
  issueA(0, 0);
  issueA(1, 1);
  SCHED0();
  for (int kt = 0; kt < nk; ++kt) {
    int b = kt & 1;
    if (kt == nk - 1) { VMW(0); } else { VMW(2); }
    SCHED0();
    writeB(b);                       // cvt+ds_write B(kt)
    if (kt + 1 < nk) issueB(kt + 1); // load B(kt+1) into regs (WAR after writeB)
    SCHED0();
    LGKM0();
    SCHED0();
    SBAR(); SCHED0();
    compute(b);
    SCHED0();
    SBAR(); SCHED0();
    if (kt + 2 < nk) { issueA(kt + 2, b); SCHED0(); }
  }

  // epilogue: h = silu(g)*u -> bf16 at row=code
#pragma unroll
  for (int mf = 0; mf < 4; ++mf) {
#pragma unroll
    for (int q = 0; q < 4; ++q) {
      int lr = wm * 64 + mf * 16 + (lane >> 4) * 4 + q;
      int grow = m0 + lr;
      if (grow < M) {
        int code = lst ? lst[grow] : grow;
        unsigned short* Hp = H + (size_t)code * Ntot + n0 + wn * 64 + (lane & 15);
#pragma unroll
        for (int nf = 0; nf < 4; ++nf) {
          float gg = accG[mf][nf][q], uu = accU[mf][nf][q];
          Hp[nf * 16] = f2bf((gg / (1.f + __expf(-gg))) * uu);
        }
      }
    }
  }
}

// ---------------- down grouped GEMM, native f32 [K][N] weights ----------------
__global__ __launch_bounds__(256, 3) void dn_kernel(
    const unsigned short* __restrict__ Hb,   // [codes][Ktot] bf16
    const float* __restrict__ Wd,            // [E][Ktot][Ntot] f32 native
    float* __restrict__ Y,                   // [codes][Ntot] f32
    const int* __restrict__ list, const int* __restrict__ cnt,
    const float* __restrict__ tw, int Ktot, int Ntot, int Mfixed) {
  int bm, bn, e;
  swz_block(bm, bn, e);
  int M = cnt ? cnt[e] : Mfixed;
  int m0 = bm * 128;
  if (m0 >= M) return;
  int n0 = bn * 128;
  const float* B0 = Wd + (size_t)e * Ktot * Ntot;
  const int* lst = list ? (list + e * TT) : nullptr;

  __shared__ __align__(16) unsigned short sA[2][4096];
  __shared__ __align__(16) unsigned short sB[2][4096];

  int tid = threadIdx.x, lane = tid & 63, w = tid >> 6;

  const unsigned short* pA[2];
#pragma unroll
  for (int q = 0; q < 2; ++q) {
    int row = q * 64 + (tid >> 2);
    int cs = (tid & 3) ^ ((row >> 1) & 3);
    int ar = min(m0 + row, M - 1);
    int code = lst ? lst[ar] : ar;
    pA[q] = Hb + (size_t)code * Ktot + cs * 8;
  }

  int kq = tid >> 5, nq = tid & 31;
  const float* pB = B0 + (size_t)(kq * 4) * Ntot + n0 + nq * 4;

  int wB[4];
#pragma unroll
  for (int i = 0; i < 4; ++i) {
    int r = nq * 4 + i;
    wB[i] = r * 32 + (((kq >> 1) ^ ((r >> 1) & 3)) * 8) + ((kq & 1) * 4);
  }

  int wm = w >> 1, wn = w & 1, cg = lane >> 4;
  int aoff[4], boff[4];
#pragma unroll
  for (int mf = 0; mf < 4; ++mf) {
    int r = wm * 64 + mf * 16 + (lane & 15);
    aoff[mf] = r * 32 + ((cg ^ ((r >> 1) & 3)) * 8);
  }
#pragma unroll
  for (int nf = 0; nf < 4; ++nf) {
    int rb = wn * 64 + nf * 16 + (lane & 15);
    boff[nf] = rb * 32 + ((cg ^ ((rb >> 1) & 3)) * 8);
  }

  f32x4 acc[4][4] = {};
  float4 rB[4];

  auto issueA = [&](int kt, int b) {
    GLOAD16(pA[0] + kt * 32, &sA[b][tid * 8]);
    GLOAD16(pA[1] + kt * 32, &sA[b][2048 + tid * 8]);
  };
  auto issueB = [&](int kt) {
#pragma unroll
    for (int j = 0; j < 4; ++j)
      rB[j] = *reinterpret_cast<const float4*>(pB + (size_t)(kt * 32 + j) * Ntot);
  };
  auto writeB = [&](int b) {
#pragma unroll
    for (int i = 0; i < 4; ++i) {
      uint2 vb{pk2(rB[0][i], rB[1][i]), pk2(rB[2][i], rB[3][i])};
      *reinterpret_cast<uint2*>(&sB[b][wB[i]]) = vb;
    }
  };
  auto compute = [&](int b) {
    bf16x8 a[4], bb[4];
#pragma unroll
    for (int mf = 0; mf < 4; ++mf)
      a[mf] = __builtin_bit_cast(bf16x8, *reinterpret_cast<const uint4*>(&sA[b][aoff[mf]]));
#pragma unroll
    for (int nf = 0; nf < 4; ++nf)
      bb[nf] = __builtin_bit_cast(bf16x8, *reinterpret_cast<const uint4*>(&sB[b][boff[nf]]));
    __builtin_amdgcn_s_setprio(1);
#pragma unroll
    for (int mf = 0; mf < 4; ++mf)
#pragma unroll
      for (int nf = 0; nf < 4; ++nf)
        acc[mf][nf] = __builtin_amdgcn_mfma_f32_16x16x32_bf16(a[mf], bb[nf], acc[mf][nf], 0, 0, 0);
    __builtin_amdgcn_s_setprio(0);
  };

  int nk = Ktot / 32;
  issueB(0);
  SCHED0();
  issueA(0, 0);
  issueA(1, 1);
  SCHED0();
  for (int kt = 0; kt < nk; ++kt) {
    int b = kt & 1;
    if (kt == nk - 1) { VMW(0); } else { VMW(2); }
    SCHED0();
    writeB(b);
    if (kt + 1 < nk) issueB(kt + 1);
    SCHED0();
    LGKM0();
    SCHED0();
    SBAR(); SCHED0();
    compute(b);
    SCHED0();
    SBAR(); SCHED0();
    if (kt + 2 < nk) { issueA(kt + 2, b); SCHED0(); }
  }

#pragma unroll
  for (int mf = 0; mf < 4; ++mf) {
#pragma unroll
    for (int q = 0; q < 4; ++q) {
      int lr = wm * 64 + mf * 16 + (lane >> 4) * 4 + q;
      int grow = m0 + lr;
      if (grow < M) {
        int code = lst ? lst[grow] : grow;
        float scale = tw ? tw[code] : 1.f;
        float* Yp = Y + (size_t)code * Ntot + n0 + wn * 64 + (lane & 15);
#pragma unroll
        for (int nf = 0; nf < 4; ++nf) Yp[nf * 16] = acc[mf][nf][q] * scale;
      }
    }
  }
}

// ---------------- combine ----------------
__global__ __launch_bounds__(256) void combine_kernel(const float* __restrict__ Y,
                                                      const float* __restrict__ Ys,
                                                      float* __restrict__ out) {
  size_t i = ((size_t)blockIdx.x * 256 + threadIdx.x) * 4;
  size_t t = i / DD;
  int d = (int)(i % DD);
  float4 a = *reinterpret_cast<const float4*>(Ys + i);
#pragma unroll
  for (int k = 0; k < 4; ++k) {
    float4 v = *reinterpret_cast<const float4*>(Y + (t * 4 + k) * (size_t)DD + d);
    a.x += v.x; a.y += v.y; a.z += v.z; a.w += v.w;
  }
  *reinterpret_cast<float4*>(out + i) = a;
}

extern "C" void kernel_launch(void* const* d_in, const int* in_sizes, int n_in,
                              void* d_out, int out_size, void* d_ws, size_t ws_size,
                              hipStream_t stream) {
  const float* x  = (const float*)d_in[0];
  const float* rw = (const float*)d_in[1];
  const float* wg = (const float*)d_in[2];
  const float* wu = (const float*)d_in[3];
  const float* wd = (const float*)d_in[4];
  const float* sg = (const float*)d_in[5];
  const float* su = (const float*)d_in[6];
  const float* sd = (const float*)d_in[7];
  float* out = (float*)d_out;

  char* ws = (char*)d_ws;
  size_t off = 0;
  auto alloc = [&](size_t bytes) {
    off = (off + 255) & ~(size_t)255;
    void* p = ws + off;
    off += bytes;
    return p;
  };
  unsigned short* Xb = (unsigned short*)alloc((size_t)TT * DD * 2);
  unsigned short* Hx = (unsigned short*)alloc((size_t)4 * TT * FF * 2);
  unsigned short* Hs = (unsigned short*)alloc((size_t)TT * FSS * 2);
  float* Y  = (float*)alloc((size_t)4 * TT * DD * 4);
  float* Ys = (float*)alloc((size_t)TT * DD * 4);
  float* tw = (float*)alloc((size_t)4 * TT * 4);
  int* cnt  = (int*)alloc(E_N * 4);
  int* list = (int*)alloc((size_t)E_N * TT * 4);
  (void)ws_size; (void)in_sizes; (void)n_in; (void)out_size;

  hipMemsetAsync(cnt, 0, E_N * 4, stream);
  cvt_bf16_kernel<<<TT * DD / 4 / 256, 256, 0, stream>>>(x, Xb);
  router_kernel<<<TT, 256, 0, stream>>>(x, rw, cnt, list, tw);

  // expert gate+up: K=D, N=F (native f32 weights)
  gu_kernel<<<dim3(TT * 4 / 128, FF / 128, E_N), 256, 0, stream>>>(
      Xb, wg, wu, Hx, list, cnt, DD, FF, 0);
  // shared gate+up: K=D, N=FS
  gu_kernel<<<dim3(TT / 128, FSS / 128, 1), 256, 0, stream>>>(
      Xb, sg, su, Hs, nullptr, nullptr, DD, FSS, TT);
  // expert down: K=F, N=D
  dn_kernel<<<dim3(TT * 4 / 128, DD / 128, E_N), 256, 0, stream>>>(
      Hx, wd, Y, list, cnt, tw, FF, DD, 0);
  // shared down: K=FS, N=D
  dn_kernel<<<dim3(TT / 128, DD / 128, 1), 256, 0, stream>>>(
      Hs, sd, Ys, nullptr, nullptr, nullptr, FSS, DD, TT);

  combine_kernel<<<TT * DD / 4 / 256, 256, 0, stream>>>(Y, Ys, out);
}

// Round 6
// 1021.316 us; speedup vs baseline: 1.1598x; 1.1598x over previous
//
#include <hip/hip_runtime.h>
#include <hip/hip_bf16.h>
#include <stdint.h>

#define E_N 16
#define TOPK 4
#define DD 2560
#define FF 1664
#define FSS 3328
#define TT 2048

#define BM 128
#define BN 128
#define BK 32

typedef __attribute__((ext_vector_type(8))) __bf16 bf16x8;
typedef __attribute__((ext_vector_type(4))) float f32x4;

__device__ __forceinline__ unsigned short f2bf(float f) {
  return __builtin_bit_cast(unsigned short, (__bf16)f);
}
__device__ __forceinline__ unsigned int pk2(float a, float b) {
  return (unsigned int)f2bf(a) | ((unsigned int)f2bf(b) << 16);
}

#define GLOAD16(g, l)                                                          \
  __builtin_amdgcn_global_load_lds(                                            \
      (const __attribute__((address_space(1))) void*)(g),                      \
      (__attribute__((address_space(3))) void*)(l), 16, 0, 0)

#define SBAR() __builtin_amdgcn_s_barrier()
#define SCHED0() __builtin_amdgcn_sched_barrier(0)
#define VMW(N) asm volatile("s_waitcnt vmcnt(" #N ")" ::: "memory")

// swizzled block decompose: XCD-chunked bijective remap (requires nwg%8==0)
__device__ __forceinline__ void swz_block(int& bm, int& bn, int& bz) {
  int gx = gridDim.x, gy = gridDim.y;
  int nwg = gx * gy * gridDim.z;
  int flat = blockIdx.x + gx * (blockIdx.y + gy * blockIdx.z);
  if ((nwg & 7) == 0) flat = (flat & 7) * (nwg >> 3) + (flat >> 3);
  bm = flat % gx;
  int rest = flat / gx;
  bn = rest % gy;
  bz = rest / gy;
}

// ---------------- X -> bf16 ----------------
__global__ __launch_bounds__(256) void cvt_bf16_kernel(const float* __restrict__ in,
                                                       unsigned short* __restrict__ out) {
  size_t i = ((size_t)blockIdx.x * 256 + threadIdx.x) * 4;
  float4 v = *reinterpret_cast<const float4*>(in + i);
  ushort4 o;
  o.x = f2bf(v.x); o.y = f2bf(v.y); o.z = f2bf(v.z); o.w = f2bf(v.w);
  *reinterpret_cast<ushort4*>(out + i) = o;
}

// ---------------- weight transpose+convert: [K][N] f32 -> [N][K] bf16 ----------------
__global__ __launch_bounds__(256) void tcvt_kernel(const float* __restrict__ in,
                                                   unsigned short* __restrict__ out,
                                                   int K, int N) {
  __shared__ float lds[64 * 65];
  int z = blockIdx.z;
  in += (size_t)z * K * N;
  out += (size_t)z * K * N;
  int k0 = blockIdx.x * 64, n0 = blockIdx.y * 64;
  int t = threadIdx.x;
#pragma unroll
  for (int j = 0; j < 4; ++j) {
    int idx = j * 256 + t;
    int r = idx >> 4, c = (idx & 15) * 4;
    float4 v = *reinterpret_cast<const float4*>(in + (size_t)(k0 + r) * N + n0 + c);
    lds[r * 65 + c] = v.x;
    lds[r * 65 + c + 1] = v.y;
    lds[r * 65 + c + 2] = v.z;
    lds[r * 65 + c + 3] = v.w;
  }
  __syncthreads();
#pragma unroll
  for (int j = 0; j < 2; ++j) {
    int idx = j * 256 + t;
    int n = idx >> 3, kg = (idx & 7) * 8;
    float a0 = lds[(kg + 0) * 65 + n], a1 = lds[(kg + 1) * 65 + n];
    float a2 = lds[(kg + 2) * 65 + n], a3 = lds[(kg + 3) * 65 + n];
    float a4 = lds[(kg + 4) * 65 + n], a5 = lds[(kg + 5) * 65 + n];
    float a6 = lds[(kg + 6) * 65 + n], a7 = lds[(kg + 7) * 65 + n];
    uint4 o{pk2(a0, a1), pk2(a2, a3), pk2(a4, a5), pk2(a6, a7)};
    *reinterpret_cast<uint4*>(out + (size_t)(n0 + n) * K + k0 + kg) = o;
  }
}

// ---------------- Router ----------------
__global__ __launch_bounds__(256) void router_kernel(const float* __restrict__ x,
                                                     const float* __restrict__ rw,
                                                     int* __restrict__ cnt,
                                                     int* __restrict__ list,
                                                     float* __restrict__ tw) {
  int t = blockIdx.x;
  const float* xr = x + (size_t)t * DD;
  __shared__ float logits[E_N];
  int lane = threadIdx.x & 63, wid = threadIdx.x >> 6;
  for (int ee = 0; ee < 4; ++ee) {
    int e = wid * 4 + ee;
    const float* wr = rw + (size_t)e * DD;
    float p = 0.f;
    for (int d = lane; d < DD; d += 64) p += xr[d] * wr[d];
#pragma unroll
    for (int off = 32; off > 0; off >>= 1) p += __shfl_down(p, off);
    if (lane == 0) logits[e] = p;
  }
  __syncthreads();
  if (threadIdx.x == 0) {
    float mx = -1e30f;
    for (int e = 0; e < E_N; ++e) mx = fmaxf(mx, logits[e]);
    float pe[E_N];
    for (int e = 0; e < E_N; ++e) pe[e] = __expf(logits[e] - mx);
    int idx[TOPK]; float val[TOPK]; float s4 = 0.f;
    unsigned used = 0;
    for (int k = 0; k < TOPK; ++k) {
      int bi = 0; float bv = -1.f;
      for (int e = 0; e < E_N; ++e)
        if (!((used >> e) & 1) && pe[e] > bv) { bv = pe[e]; bi = e; }
      used |= 1u << bi; idx[k] = bi; val[k] = bv; s4 += bv;
    }
    float inv = 1.f / s4;
    for (int k = 0; k < TOPK; ++k) {
      int e2 = idx[k];
      int pos = atomicAdd(&cnt[e2], 1);
      list[e2 * TT + pos] = t * 4 + k;
      tw[t * 4 + k] = val[k] * inv;
    }
  }
}

// ---------------- fused gate+up grouped GEMM ----------------
// LDS per buf: A[128][32] (4096 us, 64B rows) + GU[128][64] (8192 us, 128B rows;
// G chunks 0-3 | U chunks 4-7). Ring-3, single barrier per K-step.
__global__ __launch_bounds__(256, 2) void gu_kernel(
    const unsigned short* __restrict__ Xb,
    const unsigned short* __restrict__ WgT,  // [E][Ntot][Ktot] bf16
    const unsigned short* __restrict__ WuT,
    unsigned short* __restrict__ H,
    const int* __restrict__ list, const int* __restrict__ cnt,
    int Ktot, int Ntot, int Mfixed) {
  int bm, bn, e;
  swz_block(bm, bn, e);
  int M = cnt ? cnt[e] : Mfixed;
  int m0 = bm * BM;
  if (m0 >= M) return;
  int n0 = bn * BN;
  const unsigned short* Bg0 = WgT + (size_t)e * Ktot * Ntot;
  const unsigned short* Bu0 = WuT + (size_t)e * Ktot * Ntot;
  const int* lst = list ? (list + e * TT) : nullptr;

  __shared__ __align__(16) unsigned short lds[3][12288];

  int tid = threadIdx.x, lane = tid & 63, w = tid >> 6;

  // A staging: 2 issues/wave; issue J covers rows J*16..+15 (64B rows, 4 chunks)
  // source pre-swizzle: chunk c -> c ^ ((row>>1)&3)   [correct for 64B rows]
  const unsigned short* pA[2];
#pragma unroll
  for (int q = 0; q < 2; ++q) {
    int J = w * 2 + q;
    int row = J * 16 + (lane >> 2);
    int c = lane & 3;
    int cs = c ^ ((row >> 1) & 3);
    int ar = min(m0 + row, M - 1);
    int tok = lst ? (lst[ar] >> 2) : ar;
    pA[q] = Xb + (size_t)tok * Ktot + cs * 8;
  }
  // GU staging: 4 issues/wave; issue J covers rows J*8..+7 (128B rows, 8 chunks)
  // source pre-swizzle: chunk c -> c ^ (row&7)  [128B rows wrap banks: row term vanishes]
  const unsigned short* pGU[4];
#pragma unroll
  for (int q = 0; q < 4; ++q) {
    int J = w * 4 + q;
    int row = J * 8 + (lane >> 3);
    int c = lane & 7;
    int sc = c ^ (row & 7);
    pGU[q] = (sc < 4) ? (Bg0 + (size_t)(n0 + row) * Ktot + sc * 8)
                      : (Bu0 + (size_t)(n0 + row) * Ktot + (sc - 4) * 8);
  }

  auto issue = [&](int kt, int buf) {
    int koff = kt * BK;
    unsigned short* dA = &lds[buf][0];
    unsigned short* dGU = &lds[buf][4096];
#pragma unroll
    for (int q = 0; q < 2; ++q)
      GLOAD16(pA[q] + koff, dA + (w * 2 + q) * 512);
#pragma unroll
    for (int q = 0; q < 4; ++q)
      GLOAD16(pGU[q] + koff, dGU + (w * 4 + q) * 512);
  };

  int wr = (w >> 1) * 64, wc = (w & 1) * 64;
  int cg = lane >> 4;  // 0..3
  int aoff[4], goff[4], uoff[4];
#pragma unroll
  for (int m = 0; m < 4; ++m) {
    int r = wr + m * 16 + (lane & 15);
    aoff[m] = r * 32 + ((cg ^ ((r >> 1) & 3)) * 8);
  }
#pragma unroll
  for (int n = 0; n < 4; ++n) {
    int r = wc + n * 16 + (lane & 15);
    goff[n] = r * 64 + ((cg ^ (r & 7)) * 8);
    uoff[n] = r * 64 + (((cg + 4) ^ (r & 7)) * 8);
  }

  f32x4 accG[4][4] = {};
  f32x4 accU[4][4] = {};

  auto compute = [&](int buf) {
    const unsigned short* A = &lds[buf][0];
    const unsigned short* GU = &lds[buf][4096];
    bf16x8 a[4], g[4], u[4];
#pragma unroll
    for (int m = 0; m < 4; ++m)
      a[m] = __builtin_bit_cast(bf16x8, *reinterpret_cast<const uint4*>(A + aoff[m]));
#pragma unroll
    for (int n = 0; n < 4; ++n) {
      g[n] = __builtin_bit_cast(bf16x8, *reinterpret_cast<const uint4*>(GU + goff[n]));
      u[n] = __builtin_bit_cast(bf16x8, *reinterpret_cast<const uint4*>(GU + uoff[n]));
    }
    __builtin_amdgcn_s_setprio(1);
#pragma unroll
    for (int m = 0; m < 4; ++m)
#pragma unroll
      for (int n = 0; n < 4; ++n) {
        accG[m][n] = __builtin_amdgcn_mfma_f32_16x16x32_bf16(a[m], g[n], accG[m][n], 0, 0, 0);
        accU[m][n] = __builtin_amdgcn_mfma_f32_16x16x32_bf16(a[m], u[n], accU[m][n], 0, 0, 0);
      }
    __builtin_amdgcn_s_setprio(0);
  };

  int nk = Ktot / BK;
  issue(0, 0);
  issue(1, 1);
  // single barrier per iter: passing SBAR at iter kt proves all waves finished
  // compute(kt-1), so writing buf[(kt+2)%3] == buf[(kt-1)%3] after it is safe.
  for (int kt = 0; kt < nk; ++kt) {
    if (kt == nk - 1) { VMW(0); } else { VMW(6); }  // tile kt landed (own wave)
    SCHED0();
    SBAR(); SCHED0();                                // all waves' tile kt landed
    if (kt + 2 < nk) { issue(kt + 2, (kt + 2) % 3); SCHED0(); }
    compute(kt % 3);
    SCHED0();
  }

  // epilogue: h = silu(g)*u -> bf16 at row=code
#pragma unroll
  for (int m = 0; m < 4; ++m) {
#pragma unroll
    for (int r = 0; r < 4; ++r) {
      int lr = wr + m * 16 + (lane >> 4) * 4 + r;
      int grow = m0 + lr;
      if (grow < M) {
        int code = lst ? lst[grow] : grow;
        unsigned short* Hp = H + (size_t)code * Ntot + n0 + wc + (lane & 15);
#pragma unroll
        for (int n = 0; n < 4; ++n) {
          float gg = accG[m][n][r], uu = accU[m][n][r];
          Hp[n * 16] = f2bf((gg / (1.f + __expf(-gg))) * uu);
        }
      }
    }
  }
}

// ---------------- down grouped GEMM ----------------
// LDS per buf: AB[128][64] (8192 us, 128B rows; A chunks 0-3 | B chunks 4-7)
__global__ __launch_bounds__(256, 3) void dn_kernel(
    const unsigned short* __restrict__ Hb,
    const unsigned short* __restrict__ WT,   // [E][Ntot][Ktot] bf16
    float* __restrict__ Y,
    const int* __restrict__ list, const int* __restrict__ cnt,
    const float* __restrict__ tw, int Ktot, int Ntot, int Mfixed) {
  int bm, bn, e;
  swz_block(bm, bn, e);
  int M = cnt ? cnt[e] : Mfixed;
  int m0 = bm * BM;
  if (m0 >= M) return;
  int n0 = bn * BN;
  const unsigned short* B0 = WT + (size_t)e * Ktot * Ntot;
  const int* lst = list ? (list + e * TT) : nullptr;

  __shared__ __align__(16) unsigned short lds[3][8192];

  int tid = threadIdx.x, lane = tid & 63, w = tid >> 6;

  const unsigned short* pAB[4];
#pragma unroll
  for (int q = 0; q < 4; ++q) {
    int J = w * 4 + q;
    int row = J * 8 + (lane >> 3);
    int c = lane & 7;
    int sc = c ^ (row & 7);
    if (sc < 4) {
      int ar = min(m0 + row, M - 1);
      int code = lst ? lst[ar] : ar;
      pAB[q] = Hb + (size_t)code * Ktot + sc * 8;
    } else {
      pAB[q] = B0 + (size_t)(n0 + row) * Ktot + (sc - 4) * 8;
    }
  }

  auto issue = [&](int kt, int buf) {
    int koff = kt * BK;
    unsigned short* d = &lds[buf][0];
#pragma unroll
    for (int q = 0; q < 4; ++q)
      GLOAD16(pAB[q] + koff, d + (w * 4 + q) * 512);
  };

  int wr = (w >> 1) * 64, wc = (w & 1) * 64;
  int cg = lane >> 4;
  int aoff[4], boff[4];
#pragma unroll
  for (int m = 0; m < 4; ++m) {
    int r = wr + m * 16 + (lane & 15);
    aoff[m] = r * 64 + ((cg ^ (r & 7)) * 8);
  }
#pragma unroll
  for (int n = 0; n < 4; ++n) {
    int r = wc + n * 16 + (lane & 15);
    boff[n] = r * 64 + (((cg + 4) ^ (r & 7)) * 8);
  }

  f32x4 acc[4][4] = {};

  auto compute = [&](int buf) {
    const unsigned short* AB = &lds[buf][0];
    bf16x8 a[4], b[4];
#pragma unroll
    for (int m = 0; m < 4; ++m)
      a[m] = __builtin_bit_cast(bf16x8, *reinterpret_cast<const uint4*>(AB + aoff[m]));
#pragma unroll
    for (int n = 0; n < 4; ++n)
      b[n] = __builtin_bit_cast(bf16x8, *reinterpret_cast<const uint4*>(AB + boff[n]));
    __builtin_amdgcn_s_setprio(1);
#pragma unroll
    for (int m = 0; m < 4; ++m)
#pragma unroll
      for (int n = 0; n < 4; ++n)
        acc[m][n] = __builtin_amdgcn_mfma_f32_16x16x32_bf16(a[m], b[n], acc[m][n], 0, 0, 0);
    __builtin_amdgcn_s_setprio(0);
  };

  int nk = Ktot / BK;
  issue(0, 0);
  issue(1, 1);
  for (int kt = 0; kt < nk; ++kt) {
    if (kt == nk - 1) { VMW(0); } else { VMW(4); }
    SCHED0();
    SBAR(); SCHED0();
    if (kt + 2 < nk) { issue(kt + 2, (kt + 2) % 3); SCHED0(); }
    compute(kt % 3);
    SCHED0();
  }

#pragma unroll
  for (int m = 0; m < 4; ++m) {
#pragma unroll
    for (int r = 0; r < 4; ++r) {
      int lr = wr + m * 16 + (lane >> 4) * 4 + r;
      int grow = m0 + lr;
      if (grow < M) {
        int code = lst ? lst[grow] : grow;
        float scale = tw ? tw[code] : 1.f;
        float* Yp = Y + (size_t)code * Ntot + n0 + wc + (lane & 15);
#pragma unroll
        for (int n = 0; n < 4; ++n) Yp[n * 16] = acc[m][n][r] * scale;
      }
    }
  }
}

// ---------------- combine ----------------
__global__ __launch_bounds__(256) void combine_kernel(const float* __restrict__ Y,
                                                      const float* __restrict__ Ys,
                                                      float* __restrict__ out) {
  size_t i = ((size_t)blockIdx.x * 256 + threadIdx.x) * 4;
  size_t t = i / DD;
  int d = (int)(i % DD);
  float4 a = *reinterpret_cast<const float4*>(Ys + i);
#pragma unroll
  for (int k = 0; k < 4; ++k) {
    float4 v = *reinterpret_cast<const float4*>(Y + (t * 4 + k) * (size_t)DD + d);
    a.x += v.x; a.y += v.y; a.z += v.z; a.w += v.w;
  }
  *reinterpret_cast<float4*>(out + i) = a;
}

extern "C" void kernel_launch(void* const* d_in, const int* in_sizes, int n_in,
                              void* d_out, int out_size, void* d_ws, size_t ws_size,
                              hipStream_t stream) {
  const float* x  = (const float*)d_in[0];
  const float* rw = (const float*)d_in[1];
  const float* wg = (const float*)d_in[2];
  const float* wu = (const float*)d_in[3];
  const float* wd = (const float*)d_in[4];
  const float* sg = (const float*)d_in[5];
  const float* su = (const float*)d_in[6];
  const float* sd = (const float*)d_in[7];
  float* out = (float*)d_out;

  char* ws = (char*)d_ws;
  size_t off = 0;
  auto alloc = [&](size_t bytes) {
    off = (off + 255) & ~(size_t)255;
    void* p = ws + off;
    off += bytes;
    return p;
  };
  unsigned short* W1 = (unsigned short*)alloc((size_t)E_N * FF * DD * 2);   // 136 MB
  unsigned short* W2 = (unsigned short*)alloc((size_t)E_N * FF * DD * 2);   // 136 MB
  unsigned short* W3 = (unsigned short*)alloc((size_t)FSS * DD * 2);        // 17 MB
  unsigned short* W4 = (unsigned short*)alloc((size_t)FSS * DD * 2);        // 17 MB
  unsigned short* Xb = (unsigned short*)alloc((size_t)TT * DD * 2);
  unsigned short* Hx = (unsigned short*)alloc((size_t)4 * TT * FF * 2);
  unsigned short* Hs = (unsigned short*)alloc((size_t)TT * FSS * 2);
  float* Y  = (float*)alloc((size_t)4 * TT * DD * 4);
  float* Ys = (float*)alloc((size_t)TT * DD * 4);
  float* tw = (float*)alloc((size_t)4 * TT * 4);
  int* cnt  = (int*)alloc(E_N * 4);
  int* list = (int*)alloc((size_t)E_N * TT * 4);
  (void)ws_size; (void)in_sizes; (void)n_in; (void)out_size;

  hipMemsetAsync(cnt, 0, E_N * 4, stream);
  cvt_bf16_kernel<<<TT * DD / 4 / 256, 256, 0, stream>>>(x, Xb);
  router_kernel<<<TT, 256, 0, stream>>>(x, rw, cnt, list, tw);

  // --- gate/up weight transposes: [D][F(S)] -> [F(S)][D] bf16 ---
  tcvt_kernel<<<dim3(DD / 64, FF / 64, E_N), 256, 0, stream>>>(wg, W1, DD, FF);
  tcvt_kernel<<<dim3(DD / 64, FF / 64, E_N), 256, 0, stream>>>(wu, W2, DD, FF);
  tcvt_kernel<<<dim3(DD / 64, FSS / 64, 1), 256, 0, stream>>>(sg, W3, DD, FSS);
  tcvt_kernel<<<dim3(DD / 64, FSS / 64, 1), 256, 0, stream>>>(su, W4, DD, FSS);

  // --- gate+up GEMMs ---
  gu_kernel<<<dim3(TT / BM, FF / BN, E_N), 256, 0, stream>>>(
      Xb, W1, W2, Hx, list, cnt, DD, FF, 0);
  gu_kernel<<<dim3(TT / BM, FSS / BN, 1), 256, 0, stream>>>(
      Xb, W3, W4, Hs, nullptr, nullptr, DD, FSS, TT);

  // --- down weight transposes: [F(S)][D] -> [D][F(S)] bf16 (reuse W1/W2) ---
  tcvt_kernel<<<dim3(FF / 64, DD / 64, E_N), 256, 0, stream>>>(wd, W1, FF, DD);
  tcvt_kernel<<<dim3(FSS / 64, DD / 64, 1), 256, 0, stream>>>(sd, W2, FSS, DD);

  // --- down GEMMs ---
  dn_kernel<<<dim3(TT / BM, DD / BN, E_N), 256, 0, stream>>>(
      Hx, W1, Y, list, cnt, tw, FF, DD, 0);
  dn_kernel<<<dim3(TT / BM, DD / BN, 1), 256, 0, stream>>>(
      Hs, W2, Ys, nullptr, nullptr, nullptr, FSS, DD, TT);

  combine_kernel<<<TT * DD / 4 / 256, 256, 0, stream>>>(Y, Ys, out);
}